// Round 1
// baseline (928.390 us; speedup 1.0000x reference)
//
#include <hip/hip_runtime.h>

#define N_NODES 20000
#define NPAIRS  10000
#define N_EDGES 320000
#define CAP     64
#define KN      15

// params float-index layout
#define P_ALPHA 0
#define P_BETA  1
#define P_IEPS2 2
#define P_HC2   16
#define P_S2TF  116
#define P_RSC2  216

// workspace byte offsets
#define OFF_CNT    0u
#define OFF_COUNTS 80000u
#define OFF_STATS  160000u        // 65 doubles
#define OFF_NBC    160520u
#define OFF_NEIGH  240520u
#define OFF_BUF    1440520u
#define OFF_PARAMS 6560520u

// ---- 16-lane (row) reduction via DPP row_ror adds: pure VALU, no LDS pipe ----
template<int CTRL>
__device__ __forceinline__ float dpp_add(float v) {
  int s = __builtin_bit_cast(int, v);
  int r = __builtin_amdgcn_update_dpp(0, s, CTRL, 0xF, 0xF, true);
  return v + __builtin_bit_cast(float, r);
}
__device__ __forceinline__ float sum16(float v) {
  v = dpp_add<0x128>(v);   // row_ror:8
  v = dpp_add<0x124>(v);   // row_ror:4
  v = dpp_add<0x122>(v);   // row_ror:2
  v = dpp_add<0x121>(v);   // row_ror:1
  return v;                // every lane holds the 16-lane sum
}

// ---------------- kernel 1: scatter edge ids per source node ----------------
__global__ void k_scatter(const int* __restrict__ ei, int* __restrict__ cnt,
                          int* __restrict__ buf) {
  int e = blockIdx.x * blockDim.x + threadIdx.x;
  if (e >= N_EDGES) return;
  int s = ei[e];
  int slot = atomicAdd(&cnt[s], 1);
  if (slot < CAP) buf[s * CAP + slot] = e;
}

// --------- kernel 2: pick 15 smallest edge ids (== first 15 in order) -------
__global__ void k_select(const int* __restrict__ ei, const int* __restrict__ cnt,
                         const int* __restrict__ buf, int* __restrict__ nbc_g,
                         int* __restrict__ neigh, int* __restrict__ counts) {
  int v = blockIdx.x * blockDim.x + threadIdx.x;
  if (v >= N_NODES) return;
  const int* dst = ei + N_EDGES;
  int c = cnt[v];
  int cc = c < CAP ? c : CAP;
  int sel[KN];
#pragma unroll
  for (int i = 0; i < KN; i++) sel[i] = 0x7fffffff;
  for (int i = 0; i < cc; i++) {
    int e = buf[v * CAP + i];
    if (e < sel[KN - 1]) {
      int j = KN - 1;
      while (j > 0 && sel[j - 1] > e) { sel[j] = sel[j - 1]; j--; }
      sel[j] = e;
    }
  }
  int nb = c < KN ? c : KN;
  nbc_g[v] = nb;
  atomicAdd(&counts[v], 1);               // self row
  for (int r = 0; r < nb; r++) {
    int d = dst[sel[r]];
    neigh[v * KN + r] = d;
    atomicAdd(&counts[d], 1);
  }
  if (nb < KN) atomicAdd(&counts[0], KN - nb);   // masked slots read x[0] in ref
}

// --------- kernel 3: weighted feature sums for mean(M) decomposition --------
__global__ void k_stats(const float* __restrict__ x, const int* __restrict__ counts,
                        double* __restrict__ stats) {
  int lane = threadIdx.x & 63;
  int wid = threadIdx.x >> 6;
  int gw = blockIdx.x * 4 + wid;
  float accx = 0.f, acc2 = 0.f;
  for (int u = gw; u < N_NODES; u += gridDim.x * 4) {
    float w = (float)counts[u];
    float val = x[u * 64 + lane];
    accx += w * val;
    acc2 += w * val * val;
  }
#pragma unroll
  for (int off = 32; off > 0; off >>= 1) acc2 += __shfl_xor(acc2, off, 64);
  __shared__ float redx[4][64];
  __shared__ float red2[4];
  redx[wid][lane] = accx;
  if (lane == 0) red2[wid] = acc2;
  __syncthreads();
  if (threadIdx.x < 64) {
    float s = redx[0][threadIdx.x] + redx[1][threadIdx.x] +
              redx[2][threadIdx.x] + redx[3][threadIdx.x];
    atomicAdd(&stats[1 + threadIdx.x], (double)s);
  }
  if (threadIdx.x == 0)
    atomicAdd(&stats[0], (double)(red2[0] + red2[1] + red2[2] + red2[3]));
}

// --------- kernel 4: eps, alpha, hC2, s2tf, rowsumC2 ------------------------
__global__ void k_finalize(const float* __restrict__ tf, const float* __restrict__ c2,
                           const float* __restrict__ alpha0,
                           const double* __restrict__ stats, float* __restrict__ params) {
  __shared__ float tfsum[64], tfs2[64];
  int tid = threadIdx.x;
  if (tid < 64) {
    float s = 0.f, s2 = 0.f;
    for (int tm = 0; tm < 100; tm++) { float v = tf[tm * 64 + tid]; s += v; s2 += v * v; }
    tfsum[tid] = s; tfs2[tid] = s2;
  }
  if (tid < 100) {
    int t = tid / 10, mm = tid % 10;
    float h = 0.f;
    for (int r = 0; r < 10; r++) { float cv = c2[t * 100 + mm * 10 + r]; h += cv * cv; }
    params[P_HC2 + tid] = 0.1f * h;                         // hC2[t][m]
    float s2 = 0.f;
    for (int f = 0; f < 64; f++) { float v = tf[tid * 64 + f]; s2 += v * v; }
    params[P_S2TF + tid] = s2;                              // ||tf[t][m]||^2
    float rs = 0.f;
    for (int m2 = 0; m2 < 10; m2++) rs += c2[t * 100 + mm * 10 + m2];
    params[P_RSC2 + tid] = rs;                              // sum_m C2[t][r][m]
  }
  __syncthreads();
  if (tid == 0) {
    double A = stats[0] / (double)(N_NODES * 16);
    double cross = 0.0, B = 0.0;
    for (int f = 0; f < 64; f++) {
      cross += (stats[1 + f] / (double)(N_NODES * 16)) * ((double)tfsum[f] / 100.0);
      B += (double)tfs2[f];
    }
    B /= 100.0;
    double meanM = A + B - 2.0 * cross;
    float eps = (float)(0.05 * meanM) + 1e-6f;
    float a0 = alpha0[0];
    float alpha = 1.f / (1.f + expf(-a0));
    params[P_ALPHA] = alpha;
    params[P_BETA]  = 1.f - alpha;
    params[P_IEPS2] = 1.4426950408889634f / eps;   // log2(e)/eps
  }
}

// --------- kernel 5: fused M + exp-domain Sinkhorn + FGW distance -----------
__global__ void __launch_bounds__(320)
k_main(const float* __restrict__ x, const float* __restrict__ tf_g,
       const float* __restrict__ c2_g, const int* __restrict__ nbc_g,
       const int* __restrict__ neigh_g, const float* __restrict__ params,
       float* __restrict__ out) {
  __shared__ __align__(16) float tf_l[6400];        // [f4][tm][4] re-tiled
  __shared__ __align__(16) float xloc_l[2][16][68]; // padded stride
  __shared__ float s2x_l[2][16];
  __shared__ float M_l[2][1680];                    // [k*105 + tm]
  __shared__ float s2tf_l[100];
  __shared__ float bsb_l[20][16][2];                // per-group {B,SB} exchange
  __shared__ int   nbc_l[2];

  const int tid = threadIdx.x;
  const int lane = tid & 63;
  const int wid = tid >> 6;
  const int node_s = tid / 160;
  const int s = tid % 160;
  const int t = s >> 4;
  const int k = s & 15;
  const int grp = node_s * 10 + t;

  for (int i = tid; i < 6400; i += 320) {
    int tm = i >> 6, f = i & 63;
    tf_l[((f >> 2) * 100 + tm) * 4 + (f & 3)] = tf_g[i];
  }
  if (tid < 100) s2tf_l[tid] = params[P_S2TF + tid];

  const float alpha = params[P_ALPHA];
  const float beta  = params[P_BETA];
  const float ieps2 = params[P_IEPS2];
  const float twoal = 2.0f * alpha;
  const float q = 0.1f;

  float hc2reg[10], rsreg[10], c2row[10];   // t (and k) fixed per lane: load once
  {
    int kc = (k < 10) ? k : 9;
#pragma unroll
    for (int m = 0; m < 10; m++) {
      hc2reg[m] = params[P_HC2 + t * 10 + m];
      rsreg[m]  = params[P_RSC2 + t * 10 + m];
      c2row[m]  = c2_g[t * 100 + kc * 10 + m];
    }
  }

  for (int p = blockIdx.x; p < NPAIRS; p += gridDim.x) {
    __syncthreads();
    // ---- stage xloc (2 nodes x 16 rows x 64 feats), masked rows = 0 ----
    for (int idx = wid; idx < 32; idx += 5) {
      int nd = idx >> 4, r = idx & 15;
      int v = 2 * p + nd;
      int nb = nbc_g[v];
      int srcn = (r == 0) ? v : ((r - 1) < nb ? neigh_g[v * KN + (r - 1)] : -1);
      float val = (srcn >= 0) ? x[srcn * 64 + lane] : 0.0f;
      xloc_l[nd][r][lane] = val;
      float sq = val * val;
#pragma unroll
      for (int off = 32; off > 0; off >>= 1) sq += __shfl_xor(sq, off, 64);
      if (lane == 0) { s2x_l[nd][r] = sq; if (r == 0) nbc_l[nd] = nb; }
    }
    __syncthreads();
    // ---- M phase: lane = (t,m), accumulate dots for all 16 k ----
    if (s < 100) {
      float acc[16];
#pragma unroll
      for (int kk = 0; kk < 16; kk++) acc[kk] = 0.0f;
#pragma unroll 4
      for (int f4 = 0; f4 < 16; f4++) {
        const float4 tv = *(const float4*)&tf_l[(f4 * 100 + s) * 4];
#pragma unroll
        for (int kk = 0; kk < 16; kk++) {
          const float4 xv = *(const float4*)&xloc_l[node_s][kk][f4 * 4];
          acc[kk] = fmaf(xv.x, tv.x, acc[kk]);
          acc[kk] = fmaf(xv.y, tv.y, acc[kk]);
          acc[kk] = fmaf(xv.z, tv.z, acc[kk]);
          acc[kk] = fmaf(xv.w, tv.w, acc[kk]);
        }
      }
      const float s2t = s2tf_l[s];
#pragma unroll
      for (int kk = 0; kk < 16; kk++)
        M_l[node_s][kk * 105 + s] = s2x_l[node_s][kk] + s2t - 2.0f * acc[kk];
    }
    __syncthreads();
    // ---- sinkhorn phase: lane = (t,k) ----
    {
      const int v = 2 * p + node_s;
      const int nb = nbc_l[node_s];
      const float inv = 1.0f / (float)(1 + nb);
      const float pk = (k <= nb) ? inv : 0.0f;            // p (0 for masked rows)
      const float hC1k = (k == 0) ? (float)nb * inv : ((k <= nb) ? inv : 0.0f);
      float Mrow[10], cc[10], K[10], vv[10];
#pragma unroll
      for (int m = 0; m < 10; m++) {
        Mrow[m] = M_l[node_s][k * 105 + t * 10 + m];
        cc[m] = hC1k + hc2reg[m];
        vv[m] = 1.0f;
      }
      float u = 1.0f;
#pragma unroll 1
      for (int o = 0; o < 3; o++) {
        if (o == 0) {
          // Tp = p (x) q  =>  tmp rows uniform in m; use rowsum(C2)
          const float tmpc = ((k == 0) ? (float)nb * inv : inv) * q;
#pragma unroll
          for (int m = 0; m < 10; m++) {
            float gw = cc[m] - 2.0f * tmpc * rsreg[m];
            K[m] = __builtin_amdgcn_exp2f(-(beta * Mrow[m] + twoal * gw) * ieps2);
          }
        } else {
          // Tp[k][m] = u*K*v ; tmp row0 = colsum - Tp0, rows>=1 = Tp0
          float S[10], t0[10];
#pragma unroll
          for (int m = 0; m < 10; m++) {
            float tk = K[m] * vv[m] * u;
            S[m]  = sum16(tk);
            t0[m] = sum16((k == 0) ? tk : 0.0f);
          }
          float B = 0.0f, SB = 0.0f;
#pragma unroll
          for (int m = 0; m < 10; m++) {
            B  = fmaf(t0[m], c2row[m], B);     // sum_m Tp0[m]*C2[t][r=k][m]
            SB = fmaf(S[m],  c2row[m], SB);
          }
          if (k < 10) { bsb_l[grp][k][0] = B; bsb_l[grp][k][1] = SB; }
          __threadfence_block();
#pragma unroll
          for (int m = 0; m < 10; m++) {
            float2 bv = *(const float2*)&bsb_l[grp][m][0];
            float tv2 = (k == 0) ? (bv.y - bv.x) : bv.x;
            float gw = cc[m] - 2.0f * tv2;
            K[m] = __builtin_amdgcn_exp2f(-(beta * Mrow[m] + twoal * gw) * ieps2);
          }
          __threadfence_block();
        }
        // 5 exp-domain Sinkhorn iterations (u = p/(Kv), v = q/(K^T u))
#pragma unroll 1
        for (int it = 0; it < 5; it++) {
          float kv = 0.0f;
#pragma unroll
          for (int m = 0; m < 10; m++) kv = fmaf(K[m], vv[m], kv);
          u = pk * __builtin_amdgcn_rcpf(kv);
#pragma unroll
          for (int m = 0; m < 10; m++) {
            float w = sum16(K[m] * u);
            vv[m] = q * __builtin_amdgcn_rcpf(w);
          }
        }
      }
      // ---- final: Tp, gw_tens(Tp), distance ----
      {
        float S[10], t0[10], tk[10];
#pragma unroll
        for (int m = 0; m < 10; m++) {
          tk[m] = K[m] * vv[m] * u;
          S[m]  = sum16(tk[m]);
          t0[m] = sum16((k == 0) ? tk[m] : 0.0f);
        }
        float B = 0.0f, SB = 0.0f;
#pragma unroll
        for (int m = 0; m < 10; m++) {
          B  = fmaf(t0[m], c2row[m], B);
          SB = fmaf(S[m],  c2row[m], SB);
        }
        if (k < 10) { bsb_l[grp][k][0] = B; bsb_l[grp][k][1] = SB; }
        __threadfence_block();
        float dd = 0.0f;
#pragma unroll
        for (int m = 0; m < 10; m++) {
          float2 bv = *(const float2*)&bsb_l[grp][m][0];
          float tv2 = (k == 0) ? (bv.y - bv.x) : bv.x;
          float gw = cc[m] - 2.0f * tv2;
          dd = fmaf(beta * Mrow[m] + alpha * gw, tk[m], dd);
        }
        __threadfence_block();
        dd = sum16(dd);
        if (k == 0) out[v * 10 + t] = dd;
      }
    }
  }
}

extern "C" void kernel_launch(void* const* d_in, const int* in_sizes, int n_in,
                              void* d_out, int out_size, void* d_ws, size_t ws_size,
                              hipStream_t stream) {
  const float* x  = (const float*)d_in[0];
  const int*   ei = (const int*)d_in[1];
  const float* c2 = (const float*)d_in[2];
  const float* tf = (const float*)d_in[3];
  const float* a0 = (const float*)d_in[4];
  float* out = (float*)d_out;
  char* ws = (char*)d_ws;
  int*    cnt    = (int*)(ws + OFF_CNT);
  int*    counts = (int*)(ws + OFF_COUNTS);
  double* stats  = (double*)(ws + OFF_STATS);
  int*    nbc    = (int*)(ws + OFF_NBC);
  int*    neigh  = (int*)(ws + OFF_NEIGH);
  int*    buf    = (int*)(ws + OFF_BUF);
  float*  params = (float*)(ws + OFF_PARAMS);
  (void)in_sizes; (void)n_in; (void)out_size; (void)ws_size;

  hipMemsetAsync(ws, 0, OFF_STATS + 520, stream);   // zero cnt, counts, stats
  k_scatter<<<(N_EDGES + 255) / 256, 256, 0, stream>>>(ei, cnt, buf);
  k_select<<<(N_NODES + 255) / 256, 256, 0, stream>>>(ei, cnt, buf, nbc, neigh, counts);
  k_stats<<<40, 256, 0, stream>>>(x, counts, stats);
  k_finalize<<<1, 256, 0, stream>>>(tf, c2, a0, stats, params);
  k_main<<<2500, 320, 0, stream>>>(x, tf, c2, nbc, neigh, params, out);
}

// Round 2
// 577.383 us; speedup vs baseline: 1.6079x; 1.6079x over previous
//
#include <hip/hip_runtime.h>

#define N_NODES 20000
#define NPAIRS  10000
#define N_EDGES 320000
#define CAP     64
#define KN      15

typedef _Float16 half_t;
typedef _Float16 half2_t __attribute__((ext_vector_type(2)));

// params float-index layout
#define P_ALPHA 0
#define P_BETA  1
#define P_IEPS2 2
#define P_HC2   16
#define P_S2TF  116
#define P_RSC2  216

// workspace byte offsets (16B aligned where needed)
#define OFF_CNT    0u
#define OFF_COUNTS 80000u
#define OFF_STATS  160000u        // 65 doubles (520 B)
#define OFF_NBC    160528u
#define OFF_NEIGH  240528u
#define OFF_XH     1440528u       // x_h (2.56 MB) aliases old buf region
#define OFF_BUF    1440528u       // buf consumed before x_h written
#define OFF_PARAMS 6560528u

// ---- 16-lane reduction via DPP row_ror adds: pure VALU, no LDS pipe ----
template<int CTRL>
__device__ __forceinline__ float dpp_add(float v) {
  int s = __builtin_bit_cast(int, v);
  int r = __builtin_amdgcn_update_dpp(0, s, CTRL, 0xF, 0xF, true);
  return v + __builtin_bit_cast(float, r);
}
__device__ __forceinline__ float sum16(float v) {
  v = dpp_add<0x128>(v);   // row_ror:8
  v = dpp_add<0x124>(v);   // row_ror:4
  v = dpp_add<0x122>(v);   // row_ror:2
  v = dpp_add<0x121>(v);   // row_ror:1
  return v;
}
__device__ __forceinline__ float fdot2(half2_t a, half2_t b, float c) {
  return __builtin_amdgcn_fdot2(a, b, c, false);
}

// ---------------- kernel 1: scatter edge ids per source node ----------------
__global__ void k_scatter(const int* __restrict__ ei, int* __restrict__ cnt,
                          int* __restrict__ buf) {
  int e = blockIdx.x * blockDim.x + threadIdx.x;
  if (e >= N_EDGES) return;
  int s = ei[e];
  int slot = atomicAdd(&cnt[s], 1);
  if (slot < CAP) buf[s * CAP + slot] = e;
}

// ---- kernel 2: wave-per-node; select 15 smallest edge ids via ballot-rank --
// (neighbor ORDER is irrelevant: p uniform, star C1 symmetric, sums over k)
__global__ void k_select(const int* __restrict__ ei, const int* __restrict__ cnt,
                         const int* __restrict__ buf, int* __restrict__ nbc_g,
                         int* __restrict__ neigh, int* __restrict__ counts) {
  int w = (blockIdx.x * blockDim.x + threadIdx.x) >> 6;   // node
  int lane = threadIdx.x & 63;
  if (w >= N_NODES) return;
  const int* dst = ei + N_EDGES;
  int c = cnt[w];
  int cc = c < CAP ? c : CAP;
  int e = (lane < cc) ? buf[w * CAP + lane] : 0x7fffffff;
  int nb = c < KN ? c : KN;
  bool sel;
  if (cc <= KN) {                       // wave-uniform branch
    sel = lane < cc;
  } else {
    int rank = 0;
    for (int j = 0; j < CAP; j++) {
      int ej = __shfl(e, j);
      rank += (ej < e) ? 1 : 0;
    }
    sel = (e != 0x7fffffff) && (rank < KN);  // edge ids distinct -> exactly 15
  }
  unsigned long long mask = __ballot(sel);
  if (sel) {
    int pos = __popcll(mask & ((1ull << lane) - 1ull));
    int d = dst[e];
    neigh[w * KN + pos] = d;
    atomicAdd(&counts[d], 1);
  }
  if (lane == 0) {
    nbc_g[w] = nb;
    atomicAdd(&counts[w], 1);                          // self row
    if (nb < KN) atomicAdd(&counts[0], KN - nb);       // masked rows read x[0]
  }
}

// ---------------- kernel 2b: x -> f16 copy ----------------------------------
__global__ void k_x16(const float* __restrict__ x, half_t* __restrict__ xh) {
  int i = blockIdx.x * blockDim.x + threadIdx.x;   // per 4 floats
  if (i >= N_NODES * 16) return;
  float4 v = ((const float4*)x)[i];
  half2_t a = { (half_t)v.x, (half_t)v.y };
  half2_t b = { (half_t)v.z, (half_t)v.w };
  uint2 st = { __builtin_bit_cast(unsigned int, a), __builtin_bit_cast(unsigned int, b) };
  ((uint2*)xh)[i] = st;
}

// --------- kernel 3: weighted feature sums for mean(M) decomposition --------
__global__ void k_stats(const float* __restrict__ x, const int* __restrict__ counts,
                        double* __restrict__ stats) {
  int lane = threadIdx.x & 63;
  int wid = threadIdx.x >> 6;
  int gw = blockIdx.x * 4 + wid;
  float accx = 0.f, acc2 = 0.f;
  for (int u = gw; u < N_NODES; u += gridDim.x * 4) {
    float w = (float)counts[u];
    float val = x[u * 64 + lane];
    accx += w * val;
    acc2 += w * val * val;
  }
#pragma unroll
  for (int off = 32; off > 0; off >>= 1) acc2 += __shfl_xor(acc2, off, 64);
  __shared__ float redx[4][64];
  __shared__ float red2[4];
  redx[wid][lane] = accx;
  if (lane == 0) red2[wid] = acc2;
  __syncthreads();
  if (threadIdx.x < 64) {
    float s = redx[0][threadIdx.x] + redx[1][threadIdx.x] +
              redx[2][threadIdx.x] + redx[3][threadIdx.x];
    atomicAdd(&stats[1 + threadIdx.x], (double)s);
  }
  if (threadIdx.x == 0)
    atomicAdd(&stats[0], (double)(red2[0] + red2[1] + red2[2] + red2[3]));
}

// --------- kernel 4: eps, alpha, hC2, s2tf, rowsumC2 ------------------------
__global__ void k_finalize(const float* __restrict__ tf, const float* __restrict__ c2,
                           const float* __restrict__ alpha0,
                           const double* __restrict__ stats, float* __restrict__ params) {
  __shared__ float tfsum[64], tfs2[64];
  int tid = threadIdx.x;
  if (tid < 64) {
    float s = 0.f, s2 = 0.f;
    for (int tm = 0; tm < 100; tm++) { float v = tf[tm * 64 + tid]; s += v; s2 += v * v; }
    tfsum[tid] = s; tfs2[tid] = s2;
  }
  if (tid < 100) {
    int t = tid / 10, mm = tid % 10;
    float h = 0.f;
    for (int r = 0; r < 10; r++) { float cv = c2[t * 100 + mm * 10 + r]; h += cv * cv; }
    params[P_HC2 + tid] = 0.1f * h;                         // hC2[t][m]
    float s2 = 0.f;
    for (int f = 0; f < 64; f++) { float v = tf[tid * 64 + f]; s2 += v * v; }
    params[P_S2TF + tid] = s2;                              // ||tf[t][m]||^2
    float rs = 0.f;
    for (int m2 = 0; m2 < 10; m2++) rs += c2[t * 100 + mm * 10 + m2];
    params[P_RSC2 + tid] = rs;                              // sum_m C2[t][r][m]
  }
  __syncthreads();
  if (tid == 0) {
    double A = stats[0] / (double)(N_NODES * 16);
    double cross = 0.0, B = 0.0;
    for (int f = 0; f < 64; f++) {
      cross += (stats[1 + f] / (double)(N_NODES * 16)) * ((double)tfsum[f] / 100.0);
      B += (double)tfs2[f];
    }
    B /= 100.0;
    double meanM = A + B - 2.0 * cross;
    float eps = (float)(0.05 * meanM) + 1e-6f;
    float a0 = alpha0[0];
    float alpha = 1.f / (1.f + expf(-a0));
    params[P_ALPHA] = alpha;
    params[P_BETA]  = 1.f - alpha;
    params[P_IEPS2] = 1.4426950408889634f / eps;   // log2(e)/eps
  }
}

// --------- kernel 5: fused f16-M + exp-domain Sinkhorn + FGW distance -------
// lane = (node_s, t, k); M computed per-lane in registers via v_dot2_f32_f16.
// No per-pair barriers: bsb exchange is intra-wave (16-lane groups).
__global__ void __launch_bounds__(320, 4)
k_main(const half_t* __restrict__ xh, const float* __restrict__ tf_g,
       const float* __restrict__ c2_g, const int* __restrict__ nbc_g,
       const int* __restrict__ neigh_g, const float* __restrict__ params,
       float* __restrict__ out) {
  __shared__ __align__(16) half_t tf_l[6400];   // [tm][f], 12.8 KB
  __shared__ float s2tf_l[100];
  __shared__ float bsb_l[20][10][2];            // per-group {B,SB} exchange

  const int tid = threadIdx.x;
  const int node_s = tid / 160;
  const int s = tid % 160;
  const int t = s >> 4;
  const int k = s & 15;
  const int grp = node_s * 10 + t;

  for (int i = tid; i < 6400; i += 320) tf_l[i] = (half_t)tf_g[i];
  if (tid < 100) s2tf_l[tid] = params[P_S2TF + tid];

  const float alpha = params[P_ALPHA];
  const float beta  = params[P_BETA];
  const float ieps2 = params[P_IEPS2];
  const float twoal = 2.0f * alpha;
  const float q = 0.1f;

  float hc2reg[10], rsreg[10], c2row[10];   // t (and k) fixed per lane
  {
    int kc = (k < 10) ? k : 9;
#pragma unroll
    for (int m = 0; m < 10; m++) {
      hc2reg[m] = params[P_HC2 + t * 10 + m];
      rsreg[m]  = params[P_RSC2 + t * 10 + m];
      c2row[m]  = c2_g[t * 100 + kc * 10 + m];
    }
  }
  __syncthreads();

  for (int p = blockIdx.x; p < NPAIRS; p += gridDim.x) {
    const int v = 2 * p + node_s;
    const int nb = nbc_g[v];
    const int srcn = (k == 0) ? v : ((k - 1) < nb ? neigh_g[v * KN + (k - 1)] : 0);

    // ---- per-lane M row: Mrow[m] = ||x~[srcn]||^2 + ||tf[t][m]||^2 - 2 dot ----
    float acc[10], s2x = 0.0f;
    {
      const uint4* xr = (const uint4*)(xh + (size_t)srcn * 64);
      uint4 xq[8];
#pragma unroll
      for (int c = 0; c < 8; c++) xq[c] = xr[c];
#pragma unroll
      for (int m = 0; m < 10; m++) acc[m] = 0.0f;
      const half_t* tfb = &tf_l[t * 640];
#pragma unroll
      for (int c = 0; c < 8; c++) {
        half2_t x0 = __builtin_bit_cast(half2_t, xq[c].x);
        half2_t x1 = __builtin_bit_cast(half2_t, xq[c].y);
        half2_t x2 = __builtin_bit_cast(half2_t, xq[c].z);
        half2_t x3 = __builtin_bit_cast(half2_t, xq[c].w);
        s2x = fdot2(x0, x0, s2x); s2x = fdot2(x1, x1, s2x);
        s2x = fdot2(x2, x2, s2x); s2x = fdot2(x3, x3, s2x);
#pragma unroll
        for (int m = 0; m < 10; m++) {
          uint4 tq = *(const uint4*)&tfb[m * 64 + c * 8];
          float a = acc[m];
          a = fdot2(__builtin_bit_cast(half2_t, tq.x), x0, a);
          a = fdot2(__builtin_bit_cast(half2_t, tq.y), x1, a);
          a = fdot2(__builtin_bit_cast(half2_t, tq.z), x2, a);
          a = fdot2(__builtin_bit_cast(half2_t, tq.w), x3, a);
          acc[m] = a;
        }
      }
    }
    float Mrow[10];
#pragma unroll
    for (int m = 0; m < 10; m++)
      Mrow[m] = s2x + s2tf_l[t * 10 + m] - 2.0f * acc[m];

    // ---- exp-domain Sinkhorn ----
    const float inv = 1.0f / (float)(1 + nb);
    const float pk = (k <= nb) ? inv : 0.0f;
    const float hC1k = (k == 0) ? (float)nb * inv : ((k <= nb) ? inv : 0.0f);
    float K[10], vv[10];
#pragma unroll
    for (int m = 0; m < 10; m++) vv[m] = 1.0f;
    float u = 1.0f;
#pragma unroll 1
    for (int o = 0; o < 3; o++) {
      if (o == 0) {
        const float tmpc = ((k == 0) ? (float)nb * inv : inv) * q;
#pragma unroll
        for (int m = 0; m < 10; m++) {
          float gw = (hC1k + hc2reg[m]) - 2.0f * tmpc * rsreg[m];
          K[m] = __builtin_amdgcn_exp2f(-(beta * Mrow[m] + twoal * gw) * ieps2);
        }
      } else {
        float S[10], t0[10];
#pragma unroll
        for (int m = 0; m < 10; m++) {
          float tk = K[m] * vv[m] * u;
          S[m]  = sum16(tk);
          t0[m] = sum16((k == 0) ? tk : 0.0f);
        }
        float B = 0.0f, SB = 0.0f;
#pragma unroll
        for (int m = 0; m < 10; m++) {
          B  = fmaf(t0[m], c2row[m], B);
          SB = fmaf(S[m],  c2row[m], SB);
        }
        if (k < 10) { bsb_l[grp][k][0] = B; bsb_l[grp][k][1] = SB; }
        __threadfence_block();
#pragma unroll
        for (int m = 0; m < 10; m++) {
          float2 bv = *(const float2*)&bsb_l[grp][m][0];
          float tv2 = (k == 0) ? (bv.y - bv.x) : bv.x;
          float gw = (hC1k + hc2reg[m]) - 2.0f * tv2;
          K[m] = __builtin_amdgcn_exp2f(-(beta * Mrow[m] + twoal * gw) * ieps2);
        }
        __threadfence_block();
      }
#pragma unroll 1
      for (int it = 0; it < 5; it++) {
        float kv0 = 0.0f, kv1 = 0.0f;
#pragma unroll
        for (int m = 0; m < 10; m += 2) {
          kv0 = fmaf(K[m], vv[m], kv0);
          kv1 = fmaf(K[m + 1], vv[m + 1], kv1);
        }
        u = pk * __builtin_amdgcn_rcpf(kv0 + kv1);
#pragma unroll
        for (int m = 0; m < 10; m++) {
          float w = sum16(K[m] * u);
          vv[m] = q * __builtin_amdgcn_rcpf(w);
        }
      }
    }
    // ---- final: Tp, gw_tens(Tp), distance ----
    {
      float S[10], t0[10], tk[10];
#pragma unroll
      for (int m = 0; m < 10; m++) {
        tk[m] = K[m] * vv[m] * u;
        S[m]  = sum16(tk[m]);
        t0[m] = sum16((k == 0) ? tk[m] : 0.0f);
      }
      float B = 0.0f, SB = 0.0f;
#pragma unroll
      for (int m = 0; m < 10; m++) {
        B  = fmaf(t0[m], c2row[m], B);
        SB = fmaf(S[m],  c2row[m], SB);
      }
      if (k < 10) { bsb_l[grp][k][0] = B; bsb_l[grp][k][1] = SB; }
      __threadfence_block();
      float dd = 0.0f;
#pragma unroll
      for (int m = 0; m < 10; m++) {
        float2 bv = *(const float2*)&bsb_l[grp][m][0];
        float tv2 = (k == 0) ? (bv.y - bv.x) : bv.x;
        float gw = (hC1k + hc2reg[m]) - 2.0f * tv2;
        dd = fmaf(beta * Mrow[m] + alpha * gw, tk[m], dd);
      }
      __threadfence_block();
      dd = sum16(dd);
      if (k == 0) out[v * 10 + t] = dd;
    }
  }
}

extern "C" void kernel_launch(void* const* d_in, const int* in_sizes, int n_in,
                              void* d_out, int out_size, void* d_ws, size_t ws_size,
                              hipStream_t stream) {
  const float* x  = (const float*)d_in[0];
  const int*   ei = (const int*)d_in[1];
  const float* c2 = (const float*)d_in[2];
  const float* tf = (const float*)d_in[3];
  const float* a0 = (const float*)d_in[4];
  float* out = (float*)d_out;
  char* ws = (char*)d_ws;
  int*    cnt    = (int*)(ws + OFF_CNT);
  int*    counts = (int*)(ws + OFF_COUNTS);
  double* stats  = (double*)(ws + OFF_STATS);
  int*    nbc    = (int*)(ws + OFF_NBC);
  int*    neigh  = (int*)(ws + OFF_NEIGH);
  int*    buf    = (int*)(ws + OFF_BUF);
  half_t* xh     = (half_t*)(ws + OFF_XH);     // aliases buf (written after use)
  float*  params = (float*)(ws + OFF_PARAMS);
  (void)in_sizes; (void)n_in; (void)out_size; (void)ws_size;

  hipMemsetAsync(ws, 0, 160528, stream);   // zero cnt, counts, stats
  k_scatter<<<(N_EDGES + 255) / 256, 256, 0, stream>>>(ei, cnt, buf);
  k_select<<<(N_NODES * 64 + 255) / 256, 256, 0, stream>>>(ei, cnt, buf, nbc, neigh, counts);
  k_x16<<<(N_NODES * 16 + 255) / 256, 256, 0, stream>>>(x, xh);
  k_stats<<<128, 256, 0, stream>>>(x, counts, stats);
  k_finalize<<<1, 256, 0, stream>>>(tf, c2, a0, stats, params);
  k_main<<<2500, 320, 0, stream>>>(xh, tf, c2, nbc, neigh, params, out);
}

// Round 3
// 514.352 us; speedup vs baseline: 1.8050x; 1.1225x over previous
//
#include <hip/hip_runtime.h>

#define N_NODES 20000
#define NPAIRS  10000
#define N_EDGES 320000
#define CAP     64
#define KN      15

typedef _Float16 half_t;
typedef _Float16 half2_t __attribute__((ext_vector_type(2)));

// params float-index layout
#define P_ALPHA 0
#define P_BETA  1
#define P_IEPS2 2
#define P_HC2   16
#define P_S2TF  116
#define P_RSC2  216

// workspace byte offsets (16B aligned where needed)
#define OFF_CNT    0u
#define OFF_COUNTS 80000u
#define OFF_STATS  160000u        // 65 doubles (520 B)
#define OFF_NBC    160528u
#define OFF_NEIGH  240528u
#define OFF_XH     1440528u       // x_h (2.56 MB) aliases buf region
#define OFF_BUF    1440528u       // buf consumed before x_h written
#define OFF_PARAMS 6560528u

// tf_l per-template stride (halfs): 648 -> dword stride 324 = 4 (mod 32),
// so the 4 t-groups of a wave hit disjoint (or 2-way, free) bank quads.
#define TF_STRIDE 648

// ---- 16-lane reduction via DPP row_ror adds: pure VALU, no LDS pipe ----
template<int CTRL>
__device__ __forceinline__ float dpp_add(float v) {
  int s = __builtin_bit_cast(int, v);
  int r = __builtin_amdgcn_update_dpp(0, s, CTRL, 0xF, 0xF, true);
  return v + __builtin_bit_cast(float, r);
}
__device__ __forceinline__ float sum16(float v) {
  v = dpp_add<0x128>(v);   // row_ror:8
  v = dpp_add<0x124>(v);   // row_ror:4
  v = dpp_add<0x122>(v);   // row_ror:2
  v = dpp_add<0x121>(v);   // row_ror:1
  return v;
}
__device__ __forceinline__ float fdot2(half2_t a, half2_t b, float c) {
  return __builtin_amdgcn_fdot2(a, b, c, false);
}

// ---------------- kernel 1: scatter edge ids per source node ----------------
__global__ void k_scatter(const int* __restrict__ ei, int* __restrict__ cnt,
                          int* __restrict__ buf) {
  int e = blockIdx.x * blockDim.x + threadIdx.x;
  if (e >= N_EDGES) return;
  int s = ei[e];
  int slot = atomicAdd(&cnt[s], 1);
  if (slot < CAP) buf[s * CAP + slot] = e;
}

// ---- kernel 2: wave-per-node; select 15 smallest edge ids via ballot-rank --
// (neighbor ORDER is irrelevant: p uniform, star C1 symmetric, sums over k)
__global__ void k_select(const int* __restrict__ ei, const int* __restrict__ cnt,
                         const int* __restrict__ buf, int* __restrict__ nbc_g,
                         int* __restrict__ neigh, int* __restrict__ counts) {
  int w = (blockIdx.x * blockDim.x + threadIdx.x) >> 6;   // node
  int lane = threadIdx.x & 63;
  if (w >= N_NODES) return;
  const int* dst = ei + N_EDGES;
  int c = cnt[w];
  int cc = c < CAP ? c : CAP;
  int e = (lane < cc) ? buf[w * CAP + lane] : 0x7fffffff;
  int nb = c < KN ? c : KN;
  bool sel;
  if (cc <= KN) {                       // wave-uniform branch
    sel = lane < cc;
  } else {
    int rank = 0;
    for (int j = 0; j < cc; j++) {      // cc is wave-uniform (~20 typical)
      int ej = __shfl(e, j);
      rank += (ej < e) ? 1 : 0;
    }
    sel = (e != 0x7fffffff) && (rank < KN);  // edge ids distinct -> exactly 15
  }
  unsigned long long mask = __ballot(sel);
  if (sel) {
    int pos = __popcll(mask & ((1ull << lane) - 1ull));
    int d = dst[e];
    neigh[w * KN + pos] = d;
    atomicAdd(&counts[d], 1);
  }
  if (lane == 0) {
    nbc_g[w] = nb;
    atomicAdd(&counts[w], 1);                          // self row
    if (nb < KN) atomicAdd(&counts[0], KN - nb);       // masked rows read x[0]
  }
}

// --- kernel 3: weighted feature sums for mean(M) decomposition + x->f16 ----
__global__ void k_stats(const float* __restrict__ x, const int* __restrict__ counts,
                        double* __restrict__ stats, half_t* __restrict__ xh) {
  int lane = threadIdx.x & 63;
  int wid = threadIdx.x >> 6;
  int gw = blockIdx.x * 4 + wid;
  float accx = 0.f, acc2 = 0.f;
  for (int u = gw; u < N_NODES; u += gridDim.x * 4) {
    float w = (float)counts[u];
    float val = x[u * 64 + lane];
    xh[u * 64 + lane] = (half_t)val;
    accx += w * val;
    acc2 += w * val * val;
  }
#pragma unroll
  for (int off = 32; off > 0; off >>= 1) acc2 += __shfl_xor(acc2, off, 64);
  __shared__ float redx[4][64];
  __shared__ float red2[4];
  redx[wid][lane] = accx;
  if (lane == 0) red2[wid] = acc2;
  __syncthreads();
  if (threadIdx.x < 64) {
    float s = redx[0][threadIdx.x] + redx[1][threadIdx.x] +
              redx[2][threadIdx.x] + redx[3][threadIdx.x];
    atomicAdd(&stats[1 + threadIdx.x], (double)s);
  }
  if (threadIdx.x == 0)
    atomicAdd(&stats[0], (double)(red2[0] + red2[1] + red2[2] + red2[3]));
}

// --------- kernel 4: eps, alpha, hC2, s2tf, rowsumC2 ------------------------
__global__ void k_finalize(const float* __restrict__ tf, const float* __restrict__ c2,
                           const float* __restrict__ alpha0,
                           const double* __restrict__ stats, float* __restrict__ params) {
  int tid = threadIdx.x;
  if (tid < 100) {
    int t = tid / 10, mm = tid % 10;
    float h = 0.f;
    for (int r = 0; r < 10; r++) { float cv = c2[t * 100 + mm * 10 + r]; h += cv * cv; }
    params[P_HC2 + tid] = 0.1f * h;                         // hC2[t][m]
    float s2 = 0.f;
    for (int f = 0; f < 64; f++) { float v = tf[tid * 64 + f]; s2 += v * v; }
    params[P_S2TF + tid] = s2;                              // ||tf[t][m]||^2
    float rs = 0.f;
    for (int m2 = 0; m2 < 10; m2++) rs += c2[t * 100 + mm * 10 + m2];
    params[P_RSC2 + tid] = rs;                              // sum_m C2[t][r][m]
  }
  if (tid < 64) {   // wave 0: meanM via per-feature partials + shfl reduce
    float s = 0.f, s2 = 0.f;
    for (int tm = 0; tm < 100; tm++) { float v = tf[tm * 64 + tid]; s += v; s2 += v * v; }
    double inv16N = 1.0 / (double)(N_NODES * 16);
    double cross = (stats[1 + tid] * inv16N) * ((double)s / 100.0);
    double B = (double)s2 / 100.0;
    double term = B - 2.0 * cross;
#pragma unroll
    for (int off = 32; off > 0; off >>= 1) term += __shfl_xor(term, off, 64);
    if (tid == 0) {
      double A = stats[0] * inv16N;
      double meanM = A + term;
      float eps = (float)(0.05 * meanM) + 1e-6f;
      float a0 = alpha0[0];
      float alpha = 1.f / (1.f + expf(-a0));
      params[P_ALPHA] = alpha;
      params[P_BETA]  = 1.f - alpha;
      params[P_IEPS2] = 1.4426950408889634f / eps;   // log2(e)/eps
    }
  }
}

// --------- kernel 5: fused f16-M + exp-domain Sinkhorn + FGW distance -------
// lane = (node_s, t, k); M computed per-lane in registers via v_dot2_f32_f16.
// No per-pair barriers: bsb exchange is intra-wave (16-lane groups).
__global__ void __launch_bounds__(320, 2)
k_main(const half_t* __restrict__ xh, const float* __restrict__ tf_g,
       const float* __restrict__ c2_g, const int* __restrict__ nbc_g,
       const int* __restrict__ neigh_g, const float* __restrict__ params,
       float* __restrict__ out) {
  __shared__ __align__(16) half_t tf_l[10 * TF_STRIDE];   // [t][m*64+f], padded
  __shared__ float s2tf_l[100];
  __shared__ float bsb_l[20][10][2];            // per-group {B,SB} exchange

  const int tid = threadIdx.x;
  const int node_s = tid / 160;
  const int s = tid % 160;
  const int t = s >> 4;
  const int k = s & 15;
  const int grp = node_s * 10 + t;

  for (int i = tid; i < 6400; i += 320) {
    int tt = i / 640, rem = i - tt * 640;
    tf_l[tt * TF_STRIDE + rem] = (half_t)tf_g[i];
  }
  if (tid < 100) s2tf_l[tid] = params[P_S2TF + tid];

  const float alpha = params[P_ALPHA];
  const float beta  = params[P_BETA];
  const float ieps2 = params[P_IEPS2];
  const float twoal = 2.0f * alpha;
  const float q = 0.1f;

  float hc2reg[10], rsreg[10], c2row[10];   // t (and k) fixed per lane
  {
    int kc = (k < 10) ? k : 9;
#pragma unroll
    for (int m = 0; m < 10; m++) {
      hc2reg[m] = params[P_HC2 + t * 10 + m];
      rsreg[m]  = params[P_RSC2 + t * 10 + m];
      c2row[m]  = c2_g[t * 100 + kc * 10 + m];
    }
  }
  __syncthreads();

  for (int p = blockIdx.x; p < NPAIRS; p += gridDim.x) {
    const int v = 2 * p + node_s;
    const int nb = nbc_g[v];
    const int srcn = (k == 0) ? v : ((k - 1) < nb ? neigh_g[v * KN + (k - 1)] : 0);

    // ---- per-lane M row: Mrow[m] = ||x~[srcn]||^2 + ||tf[t][m]||^2 - 2 dot ----
    float acc[10], s2x = 0.0f;
    {
      const uint4* xr = (const uint4*)(xh + (size_t)srcn * 64);
      uint4 xq[8];
#pragma unroll
      for (int c = 0; c < 8; c++) xq[c] = xr[c];
#pragma unroll
      for (int m = 0; m < 10; m++) acc[m] = 0.0f;
      const half_t* tfb = &tf_l[t * TF_STRIDE];
#pragma unroll
      for (int c = 0; c < 8; c++) {
        half2_t x0 = __builtin_bit_cast(half2_t, xq[c].x);
        half2_t x1 = __builtin_bit_cast(half2_t, xq[c].y);
        half2_t x2 = __builtin_bit_cast(half2_t, xq[c].z);
        half2_t x3 = __builtin_bit_cast(half2_t, xq[c].w);
        s2x = fdot2(x0, x0, s2x); s2x = fdot2(x1, x1, s2x);
        s2x = fdot2(x2, x2, s2x); s2x = fdot2(x3, x3, s2x);
#pragma unroll
        for (int m = 0; m < 10; m++) {
          uint4 tq = *(const uint4*)&tfb[m * 64 + c * 8];
          float a = acc[m];
          a = fdot2(__builtin_bit_cast(half2_t, tq.x), x0, a);
          a = fdot2(__builtin_bit_cast(half2_t, tq.y), x1, a);
          a = fdot2(__builtin_bit_cast(half2_t, tq.z), x2, a);
          a = fdot2(__builtin_bit_cast(half2_t, tq.w), x3, a);
          acc[m] = a;
        }
      }
    }
    float Mrow[10];
#pragma unroll
    for (int m = 0; m < 10; m++)
      Mrow[m] = s2x + s2tf_l[t * 10 + m] - 2.0f * acc[m];

    // ---- exp-domain Sinkhorn ----
    const float inv = 1.0f / (float)(1 + nb);
    const float pk = (k <= nb) ? inv : 0.0f;
    const float hC1k = (k == 0) ? (float)nb * inv : ((k <= nb) ? inv : 0.0f);
    float K[10], vv[10];
#pragma unroll
    for (int m = 0; m < 10; m++) vv[m] = 1.0f;
    float u = 1.0f;
#pragma unroll 1
    for (int o = 0; o < 3; o++) {
      if (o == 0) {
        const float tmpc = ((k == 0) ? (float)nb * inv : inv) * q;
#pragma unroll
        for (int m = 0; m < 10; m++) {
          float gw = (hC1k + hc2reg[m]) - 2.0f * tmpc * rsreg[m];
          K[m] = __builtin_amdgcn_exp2f(-(beta * Mrow[m] + twoal * gw) * ieps2);
        }
      } else {
        float S[10], t0[10];
#pragma unroll
        for (int m = 0; m < 10; m++) {
          float tk = K[m] * vv[m] * u;
          S[m]  = sum16(tk);
          t0[m] = sum16((k == 0) ? tk : 0.0f);
        }
        float B = 0.0f, SB = 0.0f;
#pragma unroll
        for (int m = 0; m < 10; m++) {
          B  = fmaf(t0[m], c2row[m], B);
          SB = fmaf(S[m],  c2row[m], SB);
        }
        if (k < 10) { bsb_l[grp][k][0] = B; bsb_l[grp][k][1] = SB; }
        __threadfence_block();
#pragma unroll
        for (int m = 0; m < 10; m++) {
          float2 bv = *(const float2*)&bsb_l[grp][m][0];
          float tv2 = (k == 0) ? (bv.y - bv.x) : bv.x;
          float gw = (hC1k + hc2reg[m]) - 2.0f * tv2;
          K[m] = __builtin_amdgcn_exp2f(-(beta * Mrow[m] + twoal * gw) * ieps2);
        }
        __threadfence_block();
      }
#pragma unroll 1
      for (int it = 0; it < 5; it++) {
        float kv0 = 0.0f, kv1 = 0.0f;
#pragma unroll
        for (int m = 0; m < 10; m += 2) {
          kv0 = fmaf(K[m], vv[m], kv0);
          kv1 = fmaf(K[m + 1], vv[m + 1], kv1);
        }
        u = pk * __builtin_amdgcn_rcpf(kv0 + kv1);
#pragma unroll
        for (int m = 0; m < 10; m++) {
          float w = sum16(K[m] * u);
          vv[m] = q * __builtin_amdgcn_rcpf(w);
        }
      }
    }
    // ---- final: Tp, gw_tens(Tp), distance ----
    {
      float S[10], t0[10], tk[10];
#pragma unroll
      for (int m = 0; m < 10; m++) {
        tk[m] = K[m] * vv[m] * u;
        S[m]  = sum16(tk[m]);
        t0[m] = sum16((k == 0) ? tk[m] : 0.0f);
      }
      float B = 0.0f, SB = 0.0f;
#pragma unroll
      for (int m = 0; m < 10; m++) {
        B  = fmaf(t0[m], c2row[m], B);
        SB = fmaf(S[m],  c2row[m], SB);
      }
      if (k < 10) { bsb_l[grp][k][0] = B; bsb_l[grp][k][1] = SB; }
      __threadfence_block();
      float dd = 0.0f;
#pragma unroll
      for (int m = 0; m < 10; m++) {
        float2 bv = *(const float2*)&bsb_l[grp][m][0];
        float tv2 = (k == 0) ? (bv.y - bv.x) : bv.x;
        float gw = (hC1k + hc2reg[m]) - 2.0f * tv2;
        dd = fmaf(beta * Mrow[m] + alpha * gw, tk[m], dd);
      }
      __threadfence_block();
      dd = sum16(dd);
      if (k == 0) out[v * 10 + t] = dd;
    }
  }
}

extern "C" void kernel_launch(void* const* d_in, const int* in_sizes, int n_in,
                              void* d_out, int out_size, void* d_ws, size_t ws_size,
                              hipStream_t stream) {
  const float* x  = (const float*)d_in[0];
  const int*   ei = (const int*)d_in[1];
  const float* c2 = (const float*)d_in[2];
  const float* tf = (const float*)d_in[3];
  const float* a0 = (const float*)d_in[4];
  float* out = (float*)d_out;
  char* ws = (char*)d_ws;
  int*    cnt    = (int*)(ws + OFF_CNT);
  int*    counts = (int*)(ws + OFF_COUNTS);
  double* stats  = (double*)(ws + OFF_STATS);
  int*    nbc    = (int*)(ws + OFF_NBC);
  int*    neigh  = (int*)(ws + OFF_NEIGH);
  int*    buf    = (int*)(ws + OFF_BUF);
  half_t* xh     = (half_t*)(ws + OFF_XH);     // aliases buf (written after use)
  float*  params = (float*)(ws + OFF_PARAMS);
  (void)in_sizes; (void)n_in; (void)out_size; (void)ws_size;

  hipMemsetAsync(ws, 0, 160528, stream);   // zero cnt, counts, stats
  k_scatter<<<(N_EDGES + 255) / 256, 256, 0, stream>>>(ei, cnt, buf);
  k_select<<<(N_NODES * 64 + 255) / 256, 256, 0, stream>>>(ei, cnt, buf, nbc, neigh, counts);
  k_stats<<<128, 256, 0, stream>>>(x, counts, stats, xh);
  k_finalize<<<1, 128, 0, stream>>>(tf, c2, a0, stats, params);
  k_main<<<2500, 320, 0, stream>>>(xh, tf, c2, nbc, neigh, params, out);
}